// Round 1
// baseline (335.154 us; speedup 1.0000x reference)
//
#include <hip/hip_runtime.h>

#define N_TOK 4096
#define C_DIM 768
#define H_NUM 12
#define QKV_N 2304

typedef __attribute__((ext_vector_type(8))) short bf16x8;
typedef __attribute__((ext_vector_type(4))) float f32x4;

static __device__ __forceinline__ unsigned short f2bf(float f) {
  unsigned u = __builtin_bit_cast(unsigned, f);
  u += 0x7FFF + ((u >> 16) & 1);   // RNE
  return (unsigned short)(u >> 16);
}

// ---------------------------------------------------------------------------
// GEMM1: qkv = x @ w_qkv   (M=4096, K=768, N=2304), f32 in -> bf16 scatter out
// Q pre-scaled by 0.125; V stored transposed [H][64][N].
// ---------------------------------------------------------------------------
__global__ __launch_bounds__(256) void gemm_qkv(
    const float* __restrict__ x, const float* __restrict__ w,
    unsigned short* __restrict__ qw, unsigned short* __restrict__ kw,
    unsigned short* __restrict__ vw) {
  __shared__ unsigned short As[128 * 40];   // [m][k] pad 32->40
  __shared__ unsigned short Bs[128 * 40];   // [n][k] (transposed tile)
  const int t = threadIdx.x;
  const int lane = t & 63, wid = t >> 6;
  const int lr = lane & 15, lg = lane >> 4;
  const int m_base = blockIdx.y * 128, n_base = blockIdx.x * 128;
  const int wm = (wid >> 1) * 64, wn = (wid & 1) * 64;

  f32x4 acc[4][4];
#pragma unroll
  for (int mt = 0; mt < 4; ++mt)
#pragma unroll
    for (int nt = 0; nt < 4; ++nt) acc[mt][nt] = (f32x4){0.f, 0.f, 0.f, 0.f};

  for (int kt = 0; kt < 24; ++kt) {
    const int k0 = kt * 32;
    __syncthreads();
    // stage A: 128x32 f32 -> bf16
    {
      const int row = t >> 3, c4 = (t & 7) * 4;
#pragma unroll
      for (int rr = 0; rr < 4; ++rr) {
        const int r2 = rr * 32 + row;
        const float4 v = *reinterpret_cast<const float4*>(
            &x[(size_t)(m_base + r2) * 768 + k0 + c4]);
        unsigned short* d = &As[r2 * 40 + c4];
        d[0] = f2bf(v.x); d[1] = f2bf(v.y); d[2] = f2bf(v.z); d[3] = f2bf(v.w);
      }
    }
    // stage B transposed: 32x128 f32 -> bf16 [n][k]
    {
      const int kk0 = t >> 5, c4 = (t & 31) * 4;
#pragma unroll
      for (int rr = 0; rr < 4; ++rr) {
        const int kk = rr * 8 + kk0;
        const float4 v = *reinterpret_cast<const float4*>(
            &w[(size_t)(k0 + kk) * QKV_N + n_base + c4]);
        Bs[(c4 + 0) * 40 + kk] = f2bf(v.x);
        Bs[(c4 + 1) * 40 + kk] = f2bf(v.y);
        Bs[(c4 + 2) * 40 + kk] = f2bf(v.z);
        Bs[(c4 + 3) * 40 + kk] = f2bf(v.w);
      }
    }
    __syncthreads();
    bf16x8 af[4], bfr[4];
#pragma unroll
    for (int mt = 0; mt < 4; ++mt)
      af[mt] = *reinterpret_cast<const bf16x8*>(&As[(wm + mt * 16 + lr) * 40 + lg * 8]);
#pragma unroll
    for (int nt = 0; nt < 4; ++nt)
      bfr[nt] = *reinterpret_cast<const bf16x8*>(&Bs[(wn + nt * 16 + lr) * 40 + lg * 8]);
#pragma unroll
    for (int mt = 0; mt < 4; ++mt)
#pragma unroll
      for (int nt = 0; nt < 4; ++nt)
        acc[mt][nt] = __builtin_amdgcn_mfma_f32_16x16x32_bf16(af[mt], bfr[nt],
                                                              acc[mt][nt], 0, 0, 0);
  }
  // epilogue: scatter to Q/K/Vt
#pragma unroll
  for (int mt = 0; mt < 4; ++mt)
#pragma unroll
    for (int nt = 0; nt < 4; ++nt)
#pragma unroll
      for (int r = 0; r < 4; ++r) {
        const int m = m_base + wm + mt * 16 + lg * 4 + r;
        const int c = n_base + wn + nt * 16 + lr;
        float v = acc[mt][nt][r];
        const int which = c / 768;
        const int cc = c - which * 768;
        const int h = cc >> 6, d = cc & 63;
        if (which == 0) {
          qw[((size_t)h * N_TOK + m) * 64 + d] = f2bf(v * 0.125f);
        } else if (which == 1) {
          kw[((size_t)h * N_TOK + m) * 64 + d] = f2bf(v);
        } else {
          vw[((size_t)h * 64 + d) * N_TOK + m] = f2bf(v);
        }
      }
}

// ---------------------------------------------------------------------------
// Flash attention: per (qtile, head). 4 waves, 16 q-rows each. KV tile 64.
// Q pre-scaled. O written bf16 [N][C] at column h*64.
// ---------------------------------------------------------------------------
__global__ __launch_bounds__(256) void attn_kernel(
    const unsigned short* __restrict__ qw, const unsigned short* __restrict__ kw,
    const unsigned short* __restrict__ vw, unsigned short* __restrict__ ow) {
  __shared__ unsigned short Ks[64 * 72];      // [kv][d] pad 64->72
  __shared__ unsigned short Vs[64 * 72];      // [d][m] pad
  __shared__ unsigned short Ps[4 * 16 * 72];  // per-wave P tile [qrow][kv]
  const int t = threadIdx.x;
  const int lane = t & 63, wid = t >> 6;
  const int lr = lane & 15, lg = lane >> 4;
  const int h = blockIdx.y;
  const int q0 = blockIdx.x * 64;

  // Q fragments (A-operand): row = lane&15, k = d
  bf16x8 qf[2];
  {
    const unsigned short* qp =
        &qw[((size_t)h * N_TOK + q0 + wid * 16 + lr) * 64 + lg * 8];
    qf[0] = *reinterpret_cast<const bf16x8*>(qp);
    qf[1] = *reinterpret_cast<const bf16x8*>(qp + 32);
  }

  f32x4 acc_o[4];
#pragma unroll
  for (int nt = 0; nt < 4; ++nt) acc_o[nt] = (f32x4){0.f, 0.f, 0.f, 0.f};
  float m_run[4], l_run[4];
#pragma unroll
  for (int r = 0; r < 4; ++r) { m_run[r] = -1e30f; l_run[r] = 0.f; }

  const unsigned short* kbase = &kw[(size_t)h * N_TOK * 64];
  const unsigned short* vbase = &vw[(size_t)h * 64 * N_TOK];
  unsigned short* pw = &Ps[wid * 16 * 72];

  for (int kv = 0; kv < N_TOK; kv += 64) {
    __syncthreads();
    // stage K [64][64] and Vt [64][64]
#pragma unroll
    for (int rr = 0; rr < 2; ++rr) {
      const int s = t + rr * 256;
      const int row = s >> 3, seg = (s & 7) * 8;
      *reinterpret_cast<bf16x8*>(&Ks[row * 72 + seg]) =
          *reinterpret_cast<const bf16x8*>(&kbase[(size_t)(kv + row) * 64 + seg]);
      *reinterpret_cast<bf16x8*>(&Vs[row * 72 + seg]) =
          *reinterpret_cast<const bf16x8*>(&vbase[(size_t)row * N_TOK + kv + seg]);
    }
    __syncthreads();

    // S = Q K^T  (16 x 64 per wave)
    f32x4 s_acc[4];
#pragma unroll
    for (int nt = 0; nt < 4; ++nt) {
      const bf16x8 k0f =
          *reinterpret_cast<const bf16x8*>(&Ks[(nt * 16 + lr) * 72 + lg * 8]);
      const bf16x8 k1f =
          *reinterpret_cast<const bf16x8*>(&Ks[(nt * 16 + lr) * 72 + 32 + lg * 8]);
      f32x4 z = (f32x4){0.f, 0.f, 0.f, 0.f};
      z = __builtin_amdgcn_mfma_f32_16x16x32_bf16(qf[0], k0f, z, 0, 0, 0);
      s_acc[nt] = __builtin_amdgcn_mfma_f32_16x16x32_bf16(qf[1], k1f, z, 0, 0, 0);
    }

    // online softmax (row r lives in reg r across the 16-lane group)
    float al[4];
#pragma unroll
    for (int r = 0; r < 4; ++r) {
      float v = fmaxf(fmaxf(s_acc[0][r], s_acc[1][r]),
                      fmaxf(s_acc[2][r], s_acc[3][r]));
      v = fmaxf(v, __shfl_xor(v, 1));
      v = fmaxf(v, __shfl_xor(v, 2));
      v = fmaxf(v, __shfl_xor(v, 4));
      v = fmaxf(v, __shfl_xor(v, 8));
      const float mn = fmaxf(m_run[r], v);
      al[r] = __expf(m_run[r] - mn);
      m_run[r] = mn;
    }
    float p[4][4], rs[4] = {0.f, 0.f, 0.f, 0.f};
#pragma unroll
    for (int nt = 0; nt < 4; ++nt)
#pragma unroll
      for (int r = 0; r < 4; ++r) {
        const float pv = __expf(s_acc[nt][r] - m_run[r]);
        p[nt][r] = pv;
        rs[r] += pv;
      }
#pragma unroll
    for (int r = 0; r < 4; ++r) {
      float v = rs[r];
      v += __shfl_xor(v, 1);
      v += __shfl_xor(v, 2);
      v += __shfl_xor(v, 4);
      v += __shfl_xor(v, 8);
      l_run[r] = l_run[r] * al[r] + v;
    }
#pragma unroll
    for (int nt = 0; nt < 4; ++nt)
#pragma unroll
      for (int r = 0; r < 4; ++r) acc_o[nt][r] *= al[r];

    // P -> wave-private LDS (bf16)
#pragma unroll
    for (int nt = 0; nt < 4; ++nt)
#pragma unroll
      for (int r = 0; r < 4; ++r)
        pw[(lg * 4 + r) * 72 + nt * 16 + lr] = f2bf(p[nt][r]);
    __threadfence_block();  // order P writes before P fragment reads

    // O += P V
#pragma unroll
    for (int ks = 0; ks < 2; ++ks) {
      const bf16x8 pf =
          *reinterpret_cast<const bf16x8*>(&pw[lr * 72 + ks * 32 + lg * 8]);
#pragma unroll
      for (int nt = 0; nt < 4; ++nt) {
        const bf16x8 vf = *reinterpret_cast<const bf16x8*>(
            &Vs[(nt * 16 + lr) * 72 + ks * 32 + lg * 8]);
        acc_o[nt] = __builtin_amdgcn_mfma_f32_16x16x32_bf16(pf, vf, acc_o[nt], 0, 0, 0);
      }
    }
  }

  // normalize + store O (bf16, [N][C] layout)
  float inv[4];
#pragma unroll
  for (int r = 0; r < 4; ++r) inv[r] = 1.0f / l_run[r];
  const int qrow0 = q0 + wid * 16 + lg * 4;
#pragma unroll
  for (int nt = 0; nt < 4; ++nt)
#pragma unroll
    for (int r = 0; r < 4; ++r)
      ow[(size_t)(qrow0 + r) * C_DIM + h * 64 + nt * 16 + lr] =
          f2bf(acc_o[nt][r] * inv[r]);
}

// ---------------------------------------------------------------------------
// GEMM2: out = O @ w_proj + b_proj   (M=4096, K=768, N=768), f32 out
// ---------------------------------------------------------------------------
__global__ __launch_bounds__(256) void gemm_proj(
    const unsigned short* __restrict__ ob, const float* __restrict__ w,
    const float* __restrict__ bias, float* __restrict__ out) {
  __shared__ unsigned short As[128 * 40];
  __shared__ unsigned short Bs[128 * 40];
  const int t = threadIdx.x;
  const int lane = t & 63, wid = t >> 6;
  const int lr = lane & 15, lg = lane >> 4;
  const int m_base = blockIdx.y * 128, n_base = blockIdx.x * 128;
  const int wm = (wid >> 1) * 64, wn = (wid & 1) * 64;

  f32x4 acc[4][4];
#pragma unroll
  for (int mt = 0; mt < 4; ++mt)
#pragma unroll
    for (int nt = 0; nt < 4; ++nt) acc[mt][nt] = (f32x4){0.f, 0.f, 0.f, 0.f};

  for (int kt = 0; kt < 24; ++kt) {
    const int k0 = kt * 32;
    __syncthreads();
    // stage A: bf16 copy 128x32
#pragma unroll
    for (int rr = 0; rr < 2; ++rr) {
      const int s = t + rr * 256;
      const int row = s >> 2, sc = (s & 3) * 8;
      *reinterpret_cast<bf16x8*>(&As[row * 40 + sc]) =
          *reinterpret_cast<const bf16x8*>(&ob[(size_t)(m_base + row) * 768 + k0 + sc]);
    }
    // stage B transposed: 32x128 f32 -> bf16
    {
      const int kk0 = t >> 5, c4 = (t & 31) * 4;
#pragma unroll
      for (int rr = 0; rr < 4; ++rr) {
        const int kk = rr * 8 + kk0;
        const float4 v = *reinterpret_cast<const float4*>(
            &w[(size_t)(k0 + kk) * 768 + n_base + c4]);
        Bs[(c4 + 0) * 40 + kk] = f2bf(v.x);
        Bs[(c4 + 1) * 40 + kk] = f2bf(v.y);
        Bs[(c4 + 2) * 40 + kk] = f2bf(v.z);
        Bs[(c4 + 3) * 40 + kk] = f2bf(v.w);
      }
    }
    __syncthreads();
    bf16x8 af[4], bfr[4];
#pragma unroll
    for (int mt = 0; mt < 4; ++mt)
      af[mt] = *reinterpret_cast<const bf16x8*>(&As[(wm + mt * 16 + lr) * 40 + lg * 8]);
#pragma unroll
    for (int nt = 0; nt < 4; ++nt)
      bfr[nt] = *reinterpret_cast<const bf16x8*>(&Bs[(wn + nt * 16 + lr) * 40 + lg * 8]);
#pragma unroll
    for (int mt = 0; mt < 4; ++mt)
#pragma unroll
      for (int nt = 0; nt < 4; ++nt)
        acc[mt][nt] = __builtin_amdgcn_mfma_f32_16x16x32_bf16(af[mt], bfr[nt],
                                                              acc[mt][nt], 0, 0, 0);
  }
  // epilogue: f32 store + bias
#pragma unroll
  for (int nt = 0; nt < 4; ++nt) {
    const int n = n_base + wn + nt * 16 + lr;
    const float bv = bias[n];
#pragma unroll
    for (int mt = 0; mt < 4; ++mt)
#pragma unroll
      for (int r = 0; r < 4; ++r) {
        const int m = m_base + wm + mt * 16 + lg * 4 + r;
        out[(size_t)m * 768 + n] = acc[mt][nt][r] + bv;
      }
  }
}

extern "C" void kernel_launch(void* const* d_in, const int* in_sizes, int n_in,
                              void* d_out, int out_size, void* d_ws, size_t ws_size,
                              hipStream_t stream) {
  (void)in_sizes; (void)n_in; (void)out_size; (void)ws_size;
  const float* x = (const float*)d_in[0];
  const float* w_qkv = (const float*)d_in[1];
  const float* w_proj = (const float*)d_in[2];
  const float* b_proj = (const float*)d_in[3];
  float* out = (float*)d_out;

  unsigned short* qw = (unsigned short*)d_ws;
  unsigned short* kw = qw + (size_t)H_NUM * N_TOK * 64;
  unsigned short* vw = kw + (size_t)H_NUM * N_TOK * 64;
  unsigned short* ow = vw + (size_t)H_NUM * N_TOK * 64;

  gemm_qkv<<<dim3(QKV_N / 128, N_TOK / 128), 256, 0, stream>>>(x, w_qkv, qw, kw, vw);
  attn_kernel<<<dim3(N_TOK / 64, H_NUM), 256, 0, stream>>>(qw, kw, vw, ow);
  gemm_proj<<<dim3(C_DIM / 128, N_TOK / 128), 256, 0, stream>>>(ow, w_proj, b_proj, out);
}